// Round 14
// baseline (48.261 us; speedup 1.0000x reference)
//
#include <hip/hip_runtime.h>

// SoftSmoothAP on MI355X. B=384, C=48, D=512. Output: scalar f32 loss = 1 - AP.
//
//   simk[i,q] = clamp(<preds_i,preds_q> * 100*log2(e), +-45)  (only self-sim clamps)
//   E[q] = 2^simk[q]
//   sg(p,q) = Eq/(Eq+Ep)
//   PAIR TRICK (1 rcp per 2 sigmoids, exact):
//     sg1+sg2 = (Ep*S + 2P) / (P + Ep*S + Ep^2),  S=Eq1+Eq2, P=Eq1*Eq2
//     (pair containing q==p automatically contributes 0.5 + sg(other))
//   denom[i,p] = 0.5 + sum_all_q sg
//   loss = 1 - (1/B) sum_{i,c} sl[i,c]*w[c] *
//            sum_{p in P_c} (0.5 + sum_{q in P_c} sg) / denom[i,p]
//
// R14: mega was trans-pipe bound (rcp ~16cy/wave64). Pairwise-rcp halves denom
// trans; phase B back to entry-parallel (own-half lists, ~3-addr broadcast
// reads) + pairwise -> 90.8M padded sigE -> 13.7M pair-ops. Sim/prep = R13
// structure (prep extended with half-partitioned entry lists).

#define BB 384
#define CC 48
#define DD 512
#define HALF 192
#define MAXE 3072
#define SCALE 144.269504089f  // 100 * log2(e)

__device__ __forceinline__ float sigE(float Eq, float Ep) {
    return Eq * __builtin_amdgcn_rcpf(Eq + Ep);
}
// sum of two sigmoids with one rcp: sg(q1,p)+sg(q2,p)
__device__ __forceinline__ float pairE(float Eq1, float Eq2, float Ep) {
    float S = Eq1 + Eq2;
    float P = Eq1 * Eq2;
    float A = fmaf(Ep, S, P);          // Ep*S + P
    float den = fmaf(Ep, Ep, A);       // Ep^2 + Ep*S + P
    float num = A + P;                 // Ep*S + 2P
    return num * __builtin_amdgcn_rcpf(den);
}

// ---- 1. sim tiles (blocks 0..143 = 36 tiles x 4 k-chunks) + prep (block 144) -
__global__ __launch_bounds__(256) void simprep_kernel(
    const float* __restrict__ preds, const float* __restrict__ softlabels,
    float* __restrict__ simpart, float* __restrict__ wclass,
    int* __restrict__ cls_off, unsigned short* __restrict__ plist,
    int* __restrict__ ent_lo, int* __restrict__ ent_hi, int* __restrict__ nE3,
    float* __restrict__ out) {
    int tid = threadIdx.x;

    if (blockIdx.x < 144) {
        int t = blockIdx.x >> 2, kc = blockIdx.x & 3;
        int bi = t / 6, bj = t % 6;
        __shared__ __align__(16) float s_a[128][68];
        __shared__ __align__(16) float s_b[128][68];
        int kbase = kc * 128;
#pragma unroll
        for (int it = 0; it < 8; ++it) {
            int idx = it * 256 + tid;
            int r = idx >> 5;   // 0..63
            int c4 = idx & 31;  // 0..31
            float4 va = *reinterpret_cast<const float4*>(
                preds + (bi * 64 + r) * DD + kbase + c4 * 4);
            float4 vb = *reinterpret_cast<const float4*>(
                preds + (bj * 64 + r) * DD + kbase + c4 * 4);
            s_a[c4 * 4 + 0][r] = va.x; s_a[c4 * 4 + 1][r] = va.y;
            s_a[c4 * 4 + 2][r] = va.z; s_a[c4 * 4 + 3][r] = va.w;
            s_b[c4 * 4 + 0][r] = vb.x; s_b[c4 * 4 + 1][r] = vb.y;
            s_b[c4 * 4 + 2][r] = vb.z; s_b[c4 * 4 + 3][r] = vb.w;
        }
        __syncthreads();
        int ty = tid >> 4, tx = tid & 15;
        float4 acc0 = {0,0,0,0}, acc1 = {0,0,0,0}, acc2 = {0,0,0,0}, acc3 = {0,0,0,0};
#pragma unroll 4
        for (int k = 0; k < 128; ++k) {
            float4 a4 = *reinterpret_cast<const float4*>(&s_a[k][ty * 4]);
            float4 b4 = *reinterpret_cast<const float4*>(&s_b[k][tx * 4]);
            acc0.x += a4.x * b4.x; acc0.y += a4.x * b4.y; acc0.z += a4.x * b4.z; acc0.w += a4.x * b4.w;
            acc1.x += a4.y * b4.x; acc1.y += a4.y * b4.y; acc1.z += a4.y * b4.z; acc1.w += a4.y * b4.w;
            acc2.x += a4.z * b4.x; acc2.y += a4.z * b4.y; acc2.z += a4.z * b4.z; acc2.w += a4.z * b4.w;
            acc3.x += a4.w * b4.x; acc3.y += a4.w * b4.y; acc3.z += a4.w * b4.z; acc3.w += a4.w * b4.w;
        }
        float* dst = simpart + kc * (BB * BB) + (bi * 64 + ty * 4) * BB + bj * 64 + tx * 4;
        *reinterpret_cast<float4*>(dst + 0 * BB) = acc0;
        *reinterpret_cast<float4*>(dst + 1 * BB) = acc1;
        *reinterpret_cast<float4*>(dst + 2 * BB) = acc2;
        *reinterpret_cast<float4*>(dst + 3 * BB) = acc3;
    } else {
        // ---- prep: masks -> counts(+lo) -> 3-way scan -> plist + ent lists ----
        __shared__ unsigned int s_mlo[BB];
        __shared__ unsigned int s_mhi[BB];
        __shared__ int s_cnt[CC];
        __shared__ int s_lcnt[CC];
        __shared__ int s_soff[CC + 1];
        __shared__ int s_loff[CC + 1];
        __shared__ int s_hoff[CC + 1];
        int wave = tid >> 6, lane = tid & 63;

        for (int p = tid; p < BB; p += 256) {
            const float4* rowp = reinterpret_cast<const float4*>(softlabels + p * CC);
            unsigned int lo = 0, hi = 0;
#pragma unroll
            for (int v = 0; v < 12; ++v) {
                float4 x = rowp[v];
                unsigned int b = (x.x > 0.f ? 1u : 0u) | (x.y > 0.f ? 2u : 0u) |
                                 (x.z > 0.f ? 4u : 0u) | (x.w > 0.f ? 8u : 0u);
                if (v < 8) lo |= b << (4 * v);
                else       hi |= b << (4 * (v - 8));
            }
            s_mlo[p] = lo;
            s_mhi[p] = hi;
        }
        __syncthreads();

        for (int c = wave; c < CC; c += 4) {
            int cnt = 0, lcnt = 0;
#pragma unroll
            for (int t = 0; t < BB / 64; ++t) {
                int p = t * 64 + lane;
                bool pos = ((c < 32 ? (s_mlo[p] >> c) : (s_mhi[p] >> (c - 32))) & 1u) != 0u;
                int n = __popcll(__ballot(pos));
                cnt += n;
                if (t < 3) lcnt += n;  // p<192 <=> t<3
            }
            if (lane == 0) {
                s_cnt[c] = cnt;
                s_lcnt[c] = lcnt;
                wclass[c] = (cnt >= 4) ? (1.0f / (float)cnt) : 0.0f;
            }
        }
        __syncthreads();
        if (tid < 64) {
            int a = (tid < CC) ? s_cnt[tid] : 0;
            int l = (tid < CC) ? s_lcnt[tid] : 0;
            int hg = a - l;
#pragma unroll
            for (int d = 1; d < 64; d <<= 1) {
                int oa = __shfl_up(a, d, 64);
                int ol = __shfl_up(l, d, 64);
                int oh = __shfl_up(hg, d, 64);
                if (tid >= d) { a += oa; l += ol; hg += oh; }
            }
            if (tid < CC) { s_soff[tid + 1] = a; s_loff[tid + 1] = l; s_hoff[tid + 1] = hg; }
            if (tid == 0) { s_soff[0] = 0; s_loff[0] = 0; s_hoff[0] = 0; }
            if (tid == CC - 1) { nE3[0] = a; nE3[1] = l; nE3[2] = hg; }
        }
        __syncthreads();
        if (tid <= CC) cls_off[tid] = s_soff[tid];
        for (int c = wave; c < CC; c += 4) {
            int base = 0;
            int off = s_soff[c], L = s_lcnt[c], lo = s_loff[c], ho = s_hoff[c];
#pragma unroll
            for (int t = 0; t < BB / 64; ++t) {
                int p = t * 64 + lane;
                bool pos = ((c < 32 ? (s_mlo[p] >> c) : (s_mhi[p] >> (c - 32))) & 1u) != 0u;
                unsigned long long m = __ballot(pos);
                if (pos) {
                    int idx = base + __popcll(m & ((1ull << lane) - 1ull));
                    plist[off + idx] = (unsigned short)p;
                    int pk = (c << 16) | p;
                    if (idx < L) ent_lo[lo + idx] = pk;
                    else         ent_hi[ho + idx - L] = pk;
                }
                base += __popcll(m);
            }
        }
        if (tid == 0) out[0] = 1.0f;
    }
}

// ---- 2. mega768x576: pairwise denom + entry-parallel pairwise phase B --------
__global__ __launch_bounds__(576) void mega_kernel(
    const float* __restrict__ simpart, const float* __restrict__ softlabels,
    const float* __restrict__ wclass, const int* __restrict__ cls_off,
    const unsigned short* __restrict__ plist, const int* __restrict__ ent_lo,
    const int* __restrict__ ent_hi, const int* __restrict__ nE3,
    float* __restrict__ out) {
    int i = blockIdx.x >> 1, h = blockIdx.x & 1;
    int tid = threadIdx.x;
    int wave = tid >> 6, lane = tid & 63;

    __shared__ __align__(16) float s_E[BB];
    __shared__ float s_part[576];
    __shared__ float s_inv[HALF];
    __shared__ float s_wsl[CC];
    __shared__ int s_off[CC + 1];
    __shared__ float s_Eq[MAXE];
    __shared__ float s_red[9];

    if (tid < BB) {
        int x = i * BB + tid;
        float sim = (simpart[x] + simpart[BB * BB + x]) +
                    (simpart[2 * BB * BB + x] + simpart[3 * BB * BB + x]);
        float sk = fminf(fmaxf(sim * SCALE, -45.0f), 45.0f);  // only self-sim clamps
        s_E[tid] = __builtin_amdgcn_exp2f(sk);
    }
    if (tid < CC) s_wsl[tid] = wclass[tid] * softlabels[i * CC + tid];
    if (tid <= CC) s_off[tid] = cls_off[tid];
    __syncthreads();
    int nE = s_off[CC];
    for (int e = tid; e < nE; e += 576) s_Eq[e] = s_E[plist[e]];

    // --- denominators: 3 threads/p (128 q = 64 pairs each), 4 rcp chains ---
    {
        int pl = tid % HALF;     // lane-contiguous p
        int third = tid / HALF;  // wave-uniform q-third
        float Ep = s_E[h * HALF + pl];
        const float4* sv = reinterpret_cast<const float4*>(s_E + third * 128);
        float c0 = 0.f, c1 = 0.f, c2 = 0.f, c3 = 0.f;
#pragma unroll 4
        for (int t = 0; t < 16; ++t) {
            float4 v0 = sv[2 * t];      // same-address broadcast reads
            float4 v1 = sv[2 * t + 1];
            c0 += pairE(v0.x, v0.y, Ep);
            c1 += pairE(v0.z, v0.w, Ep);
            c2 += pairE(v1.x, v1.y, Ep);
            c3 += pairE(v1.z, v1.w, Ep);
        }
        s_part[tid] = (c0 + c1) + (c2 + c3);
    }
    __syncthreads();
    if (tid < HALF) {
        float d = 0.5f + s_part[tid] + s_part[tid + HALF] + s_part[tid + 2 * HALF];
        s_inv[tid] = __builtin_amdgcn_rcpf(d);
    }
    __syncthreads();

    // --- phase B: entry-parallel over own half; class-sorted lanes ->
    //     s_Eq reads are ~3-address broadcasts; pairwise rcp inside ---
    const int* ent = h ? ent_hi : ent_lo;
    int n = nE3[1 + h];
    float part = 0.f;
    for (int e = tid; e < n; e += 576) {
        int pk = ent[e];
        int c = pk >> 16, p = pk & 0xFFFF;
        int off = s_off[c], m = s_off[c + 1] - off;
        float Ep = s_E[p];
        int np = m >> 1;
        float b0 = 0.f, b1 = 0.f;
        int j = 0;
        for (; j + 1 < np; j += 2) {
            b0 += pairE(s_Eq[off + 2 * j],     s_Eq[off + 2 * j + 1], Ep);
            b1 += pairE(s_Eq[off + 2 * j + 2], s_Eq[off + 2 * j + 3], Ep);
        }
        if (j < np) b0 += pairE(s_Eq[off + 2 * j], s_Eq[off + 2 * j + 1], Ep);
        if (m & 1) b1 += sigE(s_Eq[off + m - 1], Ep);
        // pair containing q==p contributes 0.5+sg automatically; numerator = 0.5 + sum
        part += (0.5f + b0 + b1) * s_inv[p - h * HALF] * s_wsl[c];
    }

    for (int off = 32; off > 0; off >>= 1) part += __shfl_down(part, off, 64);
    if (lane == 0) s_red[wave] = part;
    __syncthreads();
    if (tid == 0) {
        float tot = 0.f;
#pragma unroll
        for (int w = 0; w < 9; ++w) tot += s_red[w];
        atomicAdd(out, -tot * (1.0f / (float)BB));
    }
}

extern "C" void kernel_launch(void* const* d_in, const int* in_sizes, int n_in,
                              void* d_out, int out_size, void* d_ws, size_t ws_size,
                              hipStream_t stream) {
    const float* preds = (const float*)d_in[0];       // (384,512) f32
    const float* softlabels = (const float*)d_in[1];  // (384,48) f32
    float* out = (float*)d_out;

    char* ws = (char*)d_ws;
    float*          simpart = (float*)(ws + 0);        // 4 * 589824 = 2359296
    float*          wclass  = (float*)(ws + 2359296);  // 192
    int*            cls_off = (int*)(ws + 2359488);    // 256 (49 used)
    unsigned short* plist   = (unsigned short*)(ws + 2359744);  // 6144
    int*            ent_lo  = (int*)(ws + 2365888);    // 12288
    int*            ent_hi  = (int*)(ws + 2378176);    // 12288
    int*            nE3     = (int*)(ws + 2390464);    // 12

    simprep_kernel<<<145, 256, 0, stream>>>(preds, softlabels, simpart, wclass,
                                            cls_off, plist, ent_lo, ent_hi, nE3, out);
    mega_kernel<<<BB * 2, 576, 0, stream>>>(simpart, softlabels, wclass, cls_off,
                                            plist, ent_lo, ent_hi, nE3, out);
}

// Round 15
// 44.235 us; speedup vs baseline: 1.0910x; 1.0910x over previous
//
#include <hip/hip_runtime.h>

// SoftSmoothAP on MI355X. B=384, C=48, D=512. Output: scalar f32 loss = 1 - AP.
//
//   simk[i,q] = clamp(<preds_i,preds_q> * 100*log2(e), +-45)  (only self-sim clamps)
//   E[q] = 2^simk[q];  sg(p,q) = Eq/(Eq+Ep)
//   denom[i,p] = 0.5 + sum_all_q sg   (self term = 0.5)
//   loss = 1 - (1/B) sum_{i,c} sl[i,c]*w[c] *
//            sum_{p in P_c} (0.5 + sum_{q in P_c} sg) / denom[i,p]
//
// R15 = R13 (best, 43.2us) with ONE change: phase B entry-parallel over the
// block's OWN half-lists (ent_lo/ent_hi) with sigE -- removes the 2x
// half-redundancy + 1.7x lane padding of the per-class form. Denom = R13's
// 8-chain sigE (pairE regressed). E-form = clamp+-45 (no minmax prologue).

#define BB 384
#define CC 48
#define DD 512
#define HALF 192
#define MAXE 3072
#define SCALE 144.269504089f  // 100 * log2(e)

__device__ __forceinline__ float sigE(float Eq, float Ep) {
    return Eq * __builtin_amdgcn_rcpf(Eq + Ep);
}

// ---- 1. sim tiles (blocks 0..143 = 36 tiles x 4 k-chunks) + prep (block 144) -
__global__ __launch_bounds__(256) void simprep_kernel(
    const float* __restrict__ preds, const float* __restrict__ softlabels,
    float* __restrict__ simpart, float* __restrict__ wclass,
    int* __restrict__ cls_off, unsigned short* __restrict__ plist,
    int* __restrict__ ent_lo, int* __restrict__ ent_hi, int* __restrict__ nE3,
    float* __restrict__ out) {
    int tid = threadIdx.x;

    if (blockIdx.x < 144) {
        int t = blockIdx.x >> 2, kc = blockIdx.x & 3;
        int bi = t / 6, bj = t % 6;
        __shared__ __align__(16) float s_a[128][68];
        __shared__ __align__(16) float s_b[128][68];
        int kbase = kc * 128;
#pragma unroll
        for (int it = 0; it < 8; ++it) {
            int idx = it * 256 + tid;
            int r = idx >> 5;   // 0..63
            int c4 = idx & 31;  // 0..31
            float4 va = *reinterpret_cast<const float4*>(
                preds + (bi * 64 + r) * DD + kbase + c4 * 4);
            float4 vb = *reinterpret_cast<const float4*>(
                preds + (bj * 64 + r) * DD + kbase + c4 * 4);
            s_a[c4 * 4 + 0][r] = va.x; s_a[c4 * 4 + 1][r] = va.y;
            s_a[c4 * 4 + 2][r] = va.z; s_a[c4 * 4 + 3][r] = va.w;
            s_b[c4 * 4 + 0][r] = vb.x; s_b[c4 * 4 + 1][r] = vb.y;
            s_b[c4 * 4 + 2][r] = vb.z; s_b[c4 * 4 + 3][r] = vb.w;
        }
        __syncthreads();
        int ty = tid >> 4, tx = tid & 15;
        float4 acc0 = {0,0,0,0}, acc1 = {0,0,0,0}, acc2 = {0,0,0,0}, acc3 = {0,0,0,0};
#pragma unroll 4
        for (int k = 0; k < 128; ++k) {
            float4 a4 = *reinterpret_cast<const float4*>(&s_a[k][ty * 4]);
            float4 b4 = *reinterpret_cast<const float4*>(&s_b[k][tx * 4]);
            acc0.x += a4.x * b4.x; acc0.y += a4.x * b4.y; acc0.z += a4.x * b4.z; acc0.w += a4.x * b4.w;
            acc1.x += a4.y * b4.x; acc1.y += a4.y * b4.y; acc1.z += a4.y * b4.z; acc1.w += a4.y * b4.w;
            acc2.x += a4.z * b4.x; acc2.y += a4.z * b4.y; acc2.z += a4.z * b4.z; acc2.w += a4.z * b4.w;
            acc3.x += a4.w * b4.x; acc3.y += a4.w * b4.y; acc3.z += a4.w * b4.z; acc3.w += a4.w * b4.w;
        }
        float* dst = simpart + kc * (BB * BB) + (bi * 64 + ty * 4) * BB + bj * 64 + tx * 4;
        *reinterpret_cast<float4*>(dst + 0 * BB) = acc0;
        *reinterpret_cast<float4*>(dst + 1 * BB) = acc1;
        *reinterpret_cast<float4*>(dst + 2 * BB) = acc2;
        *reinterpret_cast<float4*>(dst + 3 * BB) = acc3;
    } else {
        // ---- prep: masks -> counts(+lo) -> 3-way scan -> plist + ent lists ----
        __shared__ unsigned int s_mlo[BB];
        __shared__ unsigned int s_mhi[BB];
        __shared__ int s_cnt[CC];
        __shared__ int s_lcnt[CC];
        __shared__ int s_soff[CC + 1];
        __shared__ int s_loff[CC + 1];
        __shared__ int s_hoff[CC + 1];
        int wave = tid >> 6, lane = tid & 63;

        for (int p = tid; p < BB; p += 256) {
            const float4* rowp = reinterpret_cast<const float4*>(softlabels + p * CC);
            unsigned int lo = 0, hi = 0;
#pragma unroll
            for (int v = 0; v < 12; ++v) {
                float4 x = rowp[v];
                unsigned int b = (x.x > 0.f ? 1u : 0u) | (x.y > 0.f ? 2u : 0u) |
                                 (x.z > 0.f ? 4u : 0u) | (x.w > 0.f ? 8u : 0u);
                if (v < 8) lo |= b << (4 * v);
                else       hi |= b << (4 * (v - 8));
            }
            s_mlo[p] = lo;
            s_mhi[p] = hi;
        }
        __syncthreads();

        for (int c = wave; c < CC; c += 4) {
            int cnt = 0, lcnt = 0;
#pragma unroll
            for (int t = 0; t < BB / 64; ++t) {
                int p = t * 64 + lane;
                bool pos = ((c < 32 ? (s_mlo[p] >> c) : (s_mhi[p] >> (c - 32))) & 1u) != 0u;
                int n = __popcll(__ballot(pos));
                cnt += n;
                if (t < 3) lcnt += n;  // p<192 <=> t<3
            }
            if (lane == 0) {
                s_cnt[c] = cnt;
                s_lcnt[c] = lcnt;
                wclass[c] = (cnt >= 4) ? (1.0f / (float)cnt) : 0.0f;
            }
        }
        __syncthreads();
        if (tid < 64) {
            int a = (tid < CC) ? s_cnt[tid] : 0;
            int l = (tid < CC) ? s_lcnt[tid] : 0;
            int hg = a - l;
#pragma unroll
            for (int d = 1; d < 64; d <<= 1) {
                int oa = __shfl_up(a, d, 64);
                int ol = __shfl_up(l, d, 64);
                int oh = __shfl_up(hg, d, 64);
                if (tid >= d) { a += oa; l += ol; hg += oh; }
            }
            if (tid < CC) { s_soff[tid + 1] = a; s_loff[tid + 1] = l; s_hoff[tid + 1] = hg; }
            if (tid == 0) { s_soff[0] = 0; s_loff[0] = 0; s_hoff[0] = 0; }
            if (tid == CC - 1) { nE3[0] = a; nE3[1] = l; nE3[2] = hg; }
        }
        __syncthreads();
        if (tid <= CC) cls_off[tid] = s_soff[tid];
        for (int c = wave; c < CC; c += 4) {
            int base = 0;
            int off = s_soff[c], L = s_lcnt[c], lo = s_loff[c], ho = s_hoff[c];
#pragma unroll
            for (int t = 0; t < BB / 64; ++t) {
                int p = t * 64 + lane;
                bool pos = ((c < 32 ? (s_mlo[p] >> c) : (s_mhi[p] >> (c - 32))) & 1u) != 0u;
                unsigned long long m = __ballot(pos);
                if (pos) {
                    int idx = base + __popcll(m & ((1ull << lane) - 1ull));
                    plist[off + idx] = (unsigned short)p;
                    int pk = (c << 16) | p;
                    if (idx < L) ent_lo[lo + idx] = pk;
                    else         ent_hi[ho + idx - L] = pk;
                }
                base += __popcll(m);
            }
        }
        if (tid == 0) out[0] = 1.0f;
    }
}

// ---- 2. mega768x576: 8-chain sigE denom + own-half entry-parallel phase B ----
__global__ __launch_bounds__(576) void mega_kernel(
    const float* __restrict__ simpart, const float* __restrict__ softlabels,
    const float* __restrict__ wclass, const int* __restrict__ cls_off,
    const unsigned short* __restrict__ plist, const int* __restrict__ ent_lo,
    const int* __restrict__ ent_hi, const int* __restrict__ nE3,
    float* __restrict__ out) {
    int i = blockIdx.x >> 1, h = blockIdx.x & 1;
    int tid = threadIdx.x;
    int wave = tid >> 6, lane = tid & 63;

    __shared__ __align__(16) float s_E[BB];
    __shared__ float s_part[576];
    __shared__ float s_inv[HALF];
    __shared__ float s_wsl[CC];
    __shared__ int s_off[CC + 1];
    __shared__ float s_Eq[MAXE];
    __shared__ float s_red[9];

    if (tid < BB) {
        int x = i * BB + tid;
        float sim = (simpart[x] + simpart[BB * BB + x]) +
                    (simpart[2 * BB * BB + x] + simpart[3 * BB * BB + x]);
        float sk = fminf(fmaxf(sim * SCALE, -45.0f), 45.0f);  // only self-sim clamps
        s_E[tid] = __builtin_amdgcn_exp2f(sk);
    }
    if (tid < CC) s_wsl[tid] = wclass[tid] * softlabels[i * CC + tid];
    if (tid <= CC) s_off[tid] = cls_off[tid];
    __syncthreads();
    int nE = s_off[CC];
    for (int e = tid; e < nE; e += 576) s_Eq[e] = s_E[plist[e]];

    // --- denominators: 3 threads/p (128 q each), 8 independent sigE chains ---
    {
        int pl = tid % HALF;     // lane-contiguous p
        int third = tid / HALF;  // wave-uniform q-third
        float Ep = s_E[h * HALF + pl];
        const float4* sv = reinterpret_cast<const float4*>(s_E + third * 128);
        float a0 = 0.f, a1 = 0.f, a2 = 0.f, a3 = 0.f;
        float a4 = 0.f, a5 = 0.f, a6 = 0.f, a7 = 0.f;
#pragma unroll 4
        for (int t = 0; t < 16; ++t) {
            float4 v0 = sv[2 * t];      // same-address broadcast reads
            float4 v1 = sv[2 * t + 1];
            a0 += sigE(v0.x, Ep);
            a1 += sigE(v0.y, Ep);
            a2 += sigE(v0.z, Ep);
            a3 += sigE(v0.w, Ep);
            a4 += sigE(v1.x, Ep);
            a5 += sigE(v1.y, Ep);
            a6 += sigE(v1.z, Ep);
            a7 += sigE(v1.w, Ep);
        }
        s_part[tid] = ((a0 + a1) + (a2 + a3)) + ((a4 + a5) + (a6 + a7));
    }
    __syncthreads();
    if (tid < HALF) {
        float d = 0.5f + s_part[tid] + s_part[tid + HALF] + s_part[tid + 2 * HALF];
        s_inv[tid] = __builtin_amdgcn_rcpf(d);
    }
    __syncthreads();

    // --- phase B: entry-parallel over OWN half's entries, sigE 4-unroll ---
    const int* ent = h ? ent_hi : ent_lo;
    int n = nE3[1 + h];
    float part = 0.f;
    for (int e = tid; e < n; e += 576) {
        int pk = ent[e];
        int c = pk >> 16, p = pk & 0xFFFF;
        int off = s_off[c], m = s_off[c + 1] - off;
        float Ep = s_E[p];
        float b0 = 0.f, b1 = 0.f, b2 = 0.f, b3 = 0.f;
        int j = 0;
        for (; j + 3 < m; j += 4) {
            b0 += sigE(s_Eq[off + j], Ep);
            b1 += sigE(s_Eq[off + j + 1], Ep);
            b2 += sigE(s_Eq[off + j + 2], Ep);
            b3 += sigE(s_Eq[off + j + 3], Ep);
        }
        for (; j < m; ++j) b0 += sigE(s_Eq[off + j], Ep);
        float s = (b0 + b1) + (b2 + b3);
        // s includes q==p (=0.5): numerator = 0.5 + s
        part += (0.5f + s) * s_inv[p - h * HALF] * s_wsl[c];
    }

    for (int off = 32; off > 0; off >>= 1) part += __shfl_down(part, off, 64);
    if (lane == 0) s_red[wave] = part;
    __syncthreads();
    if (tid == 0) {
        float tot = 0.f;
#pragma unroll
        for (int w = 0; w < 9; ++w) tot += s_red[w];
        atomicAdd(out, -tot * (1.0f / (float)BB));
    }
}

extern "C" void kernel_launch(void* const* d_in, const int* in_sizes, int n_in,
                              void* d_out, int out_size, void* d_ws, size_t ws_size,
                              hipStream_t stream) {
    const float* preds = (const float*)d_in[0];       // (384,512) f32
    const float* softlabels = (const float*)d_in[1];  // (384,48) f32
    float* out = (float*)d_out;

    char* ws = (char*)d_ws;
    float*          simpart = (float*)(ws + 0);        // 4 * 589824 = 2359296
    float*          wclass  = (float*)(ws + 2359296);  // 192
    int*            cls_off = (int*)(ws + 2359488);    // 256 (49 used)
    unsigned short* plist   = (unsigned short*)(ws + 2359744);  // 6144
    int*            ent_lo  = (int*)(ws + 2365888);    // 12288
    int*            ent_hi  = (int*)(ws + 2378176);    // 12288
    int*            nE3     = (int*)(ws + 2390464);    // 12

    simprep_kernel<<<145, 256, 0, stream>>>(preds, softlabels, simpart, wclass,
                                            cls_off, plist, ent_lo, ent_hi, nE3, out);
    mega_kernel<<<BB * 2, 576, 0, stream>>>(simpart, softlabels, wclass, cls_off,
                                            plist, ent_lo, ent_hi, nE3, out);
}

// Round 16
// 44.159 us; speedup vs baseline: 1.0929x; 1.0017x over previous
//
#include <hip/hip_runtime.h>

// SoftSmoothAP on MI355X. B=384, C=48, D=512. Output: scalar f32 loss = 1 - AP.
//
//   simk[i,q] = clamp(<preds_i,preds_q> * 100*log2(e), +-45)  (only self-sim clamps)
//   E[q] = 2^simk[q];  sg(p,q) = Eq/(Eq+Ep)
//   denom[i,p] = 0.5 + sum_all_q sg   (self term = 0.5)
//   loss = 1 - (1/B) sum_{i,c} sl[i,c]*w[c] *
//            sum_{p in P_c} (0.5 + sum_{q in P_c} sg) / denom[i,p]
//
// R16 = R15 + __launch_bounds__(576, 6) on mega: suspicion is mega's VGPR
// count crossed the 64-reg occupancy cliff (waves/EU halve at 64/128), leaving
// 1 block/CU -> 3 serial grid rounds = the unexplained 3x over issue-floor.
// The bound forces the allocator to keep >=6 waves/EU (>=2.7 blocks/CU).

#define BB 384
#define CC 48
#define DD 512
#define HALF 192
#define MAXE 3072
#define SCALE 144.269504089f  // 100 * log2(e)

__device__ __forceinline__ float sigE(float Eq, float Ep) {
    return Eq * __builtin_amdgcn_rcpf(Eq + Ep);
}

// ---- 1. sim tiles (blocks 0..143 = 36 tiles x 4 k-chunks) + prep (block 144) -
__global__ __launch_bounds__(256) void simprep_kernel(
    const float* __restrict__ preds, const float* __restrict__ softlabels,
    float* __restrict__ simpart, float* __restrict__ wclass,
    int* __restrict__ cls_off, unsigned short* __restrict__ plist,
    int* __restrict__ ent_lo, int* __restrict__ ent_hi, int* __restrict__ nE3,
    float* __restrict__ out) {
    int tid = threadIdx.x;

    if (blockIdx.x < 144) {
        int t = blockIdx.x >> 2, kc = blockIdx.x & 3;
        int bi = t / 6, bj = t % 6;
        __shared__ __align__(16) float s_a[128][68];
        __shared__ __align__(16) float s_b[128][68];
        int kbase = kc * 128;
#pragma unroll
        for (int it = 0; it < 8; ++it) {
            int idx = it * 256 + tid;
            int r = idx >> 5;   // 0..63
            int c4 = idx & 31;  // 0..31
            float4 va = *reinterpret_cast<const float4*>(
                preds + (bi * 64 + r) * DD + kbase + c4 * 4);
            float4 vb = *reinterpret_cast<const float4*>(
                preds + (bj * 64 + r) * DD + kbase + c4 * 4);
            s_a[c4 * 4 + 0][r] = va.x; s_a[c4 * 4 + 1][r] = va.y;
            s_a[c4 * 4 + 2][r] = va.z; s_a[c4 * 4 + 3][r] = va.w;
            s_b[c4 * 4 + 0][r] = vb.x; s_b[c4 * 4 + 1][r] = vb.y;
            s_b[c4 * 4 + 2][r] = vb.z; s_b[c4 * 4 + 3][r] = vb.w;
        }
        __syncthreads();
        int ty = tid >> 4, tx = tid & 15;
        float4 acc0 = {0,0,0,0}, acc1 = {0,0,0,0}, acc2 = {0,0,0,0}, acc3 = {0,0,0,0};
#pragma unroll 4
        for (int k = 0; k < 128; ++k) {
            float4 a4 = *reinterpret_cast<const float4*>(&s_a[k][ty * 4]);
            float4 b4 = *reinterpret_cast<const float4*>(&s_b[k][tx * 4]);
            acc0.x += a4.x * b4.x; acc0.y += a4.x * b4.y; acc0.z += a4.x * b4.z; acc0.w += a4.x * b4.w;
            acc1.x += a4.y * b4.x; acc1.y += a4.y * b4.y; acc1.z += a4.y * b4.z; acc1.w += a4.y * b4.w;
            acc2.x += a4.z * b4.x; acc2.y += a4.z * b4.y; acc2.z += a4.z * b4.z; acc2.w += a4.z * b4.w;
            acc3.x += a4.w * b4.x; acc3.y += a4.w * b4.y; acc3.z += a4.w * b4.z; acc3.w += a4.w * b4.w;
        }
        float* dst = simpart + kc * (BB * BB) + (bi * 64 + ty * 4) * BB + bj * 64 + tx * 4;
        *reinterpret_cast<float4*>(dst + 0 * BB) = acc0;
        *reinterpret_cast<float4*>(dst + 1 * BB) = acc1;
        *reinterpret_cast<float4*>(dst + 2 * BB) = acc2;
        *reinterpret_cast<float4*>(dst + 3 * BB) = acc3;
    } else {
        // ---- prep: masks -> counts(+lo) -> 3-way scan -> plist + ent lists ----
        __shared__ unsigned int s_mlo[BB];
        __shared__ unsigned int s_mhi[BB];
        __shared__ int s_cnt[CC];
        __shared__ int s_lcnt[CC];
        __shared__ int s_soff[CC + 1];
        __shared__ int s_loff[CC + 1];
        __shared__ int s_hoff[CC + 1];
        int wave = tid >> 6, lane = tid & 63;

        for (int p = tid; p < BB; p += 256) {
            const float4* rowp = reinterpret_cast<const float4*>(softlabels + p * CC);
            unsigned int lo = 0, hi = 0;
#pragma unroll
            for (int v = 0; v < 12; ++v) {
                float4 x = rowp[v];
                unsigned int b = (x.x > 0.f ? 1u : 0u) | (x.y > 0.f ? 2u : 0u) |
                                 (x.z > 0.f ? 4u : 0u) | (x.w > 0.f ? 8u : 0u);
                if (v < 8) lo |= b << (4 * v);
                else       hi |= b << (4 * (v - 8));
            }
            s_mlo[p] = lo;
            s_mhi[p] = hi;
        }
        __syncthreads();

        for (int c = wave; c < CC; c += 4) {
            int cnt = 0, lcnt = 0;
#pragma unroll
            for (int t = 0; t < BB / 64; ++t) {
                int p = t * 64 + lane;
                bool pos = ((c < 32 ? (s_mlo[p] >> c) : (s_mhi[p] >> (c - 32))) & 1u) != 0u;
                int n = __popcll(__ballot(pos));
                cnt += n;
                if (t < 3) lcnt += n;  // p<192 <=> t<3
            }
            if (lane == 0) {
                s_cnt[c] = cnt;
                s_lcnt[c] = lcnt;
                wclass[c] = (cnt >= 4) ? (1.0f / (float)cnt) : 0.0f;
            }
        }
        __syncthreads();
        if (tid < 64) {
            int a = (tid < CC) ? s_cnt[tid] : 0;
            int l = (tid < CC) ? s_lcnt[tid] : 0;
            int hg = a - l;
#pragma unroll
            for (int d = 1; d < 64; d <<= 1) {
                int oa = __shfl_up(a, d, 64);
                int ol = __shfl_up(l, d, 64);
                int oh = __shfl_up(hg, d, 64);
                if (tid >= d) { a += oa; l += ol; hg += oh; }
            }
            if (tid < CC) { s_soff[tid + 1] = a; s_loff[tid + 1] = l; s_hoff[tid + 1] = hg; }
            if (tid == 0) { s_soff[0] = 0; s_loff[0] = 0; s_hoff[0] = 0; }
            if (tid == CC - 1) { nE3[0] = a; nE3[1] = l; nE3[2] = hg; }
        }
        __syncthreads();
        if (tid <= CC) cls_off[tid] = s_soff[tid];
        for (int c = wave; c < CC; c += 4) {
            int base = 0;
            int off = s_soff[c], L = s_lcnt[c], lo = s_loff[c], ho = s_hoff[c];
#pragma unroll
            for (int t = 0; t < BB / 64; ++t) {
                int p = t * 64 + lane;
                bool pos = ((c < 32 ? (s_mlo[p] >> c) : (s_mhi[p] >> (c - 32))) & 1u) != 0u;
                unsigned long long m = __ballot(pos);
                if (pos) {
                    int idx = base + __popcll(m & ((1ull << lane) - 1ull));
                    plist[off + idx] = (unsigned short)p;
                    int pk = (c << 16) | p;
                    if (idx < L) ent_lo[lo + idx] = pk;
                    else         ent_hi[ho + idx - L] = pk;
                }
                base += __popcll(m);
            }
        }
        if (tid == 0) out[0] = 1.0f;
    }
}

// ---- 2. mega768x576: 8-chain sigE denom + own-half entry-parallel phase B ----
__global__ __launch_bounds__(576, 6) void mega_kernel(
    const float* __restrict__ simpart, const float* __restrict__ softlabels,
    const float* __restrict__ wclass, const int* __restrict__ cls_off,
    const unsigned short* __restrict__ plist, const int* __restrict__ ent_lo,
    const int* __restrict__ ent_hi, const int* __restrict__ nE3,
    float* __restrict__ out) {
    int i = blockIdx.x >> 1, h = blockIdx.x & 1;
    int tid = threadIdx.x;
    int wave = tid >> 6, lane = tid & 63;

    __shared__ __align__(16) float s_E[BB];
    __shared__ float s_part[576];
    __shared__ float s_inv[HALF];
    __shared__ float s_wsl[CC];
    __shared__ int s_off[CC + 1];
    __shared__ float s_Eq[MAXE];
    __shared__ float s_red[9];

    if (tid < BB) {
        int x = i * BB + tid;
        float sim = (simpart[x] + simpart[BB * BB + x]) +
                    (simpart[2 * BB * BB + x] + simpart[3 * BB * BB + x]);
        float sk = fminf(fmaxf(sim * SCALE, -45.0f), 45.0f);  // only self-sim clamps
        s_E[tid] = __builtin_amdgcn_exp2f(sk);
    }
    if (tid < CC) s_wsl[tid] = wclass[tid] * softlabels[i * CC + tid];
    if (tid <= CC) s_off[tid] = cls_off[tid];
    __syncthreads();
    int nE = s_off[CC];
    for (int e = tid; e < nE; e += 576) s_Eq[e] = s_E[plist[e]];

    // --- denominators: 3 threads/p (128 q each), 8 independent sigE chains ---
    {
        int pl = tid % HALF;     // lane-contiguous p
        int third = tid / HALF;  // wave-uniform q-third
        float Ep = s_E[h * HALF + pl];
        const float4* sv = reinterpret_cast<const float4*>(s_E + third * 128);
        float a0 = 0.f, a1 = 0.f, a2 = 0.f, a3 = 0.f;
        float a4 = 0.f, a5 = 0.f, a6 = 0.f, a7 = 0.f;
#pragma unroll 4
        for (int t = 0; t < 16; ++t) {
            float4 v0 = sv[2 * t];      // same-address broadcast reads
            float4 v1 = sv[2 * t + 1];
            a0 += sigE(v0.x, Ep);
            a1 += sigE(v0.y, Ep);
            a2 += sigE(v0.z, Ep);
            a3 += sigE(v0.w, Ep);
            a4 += sigE(v1.x, Ep);
            a5 += sigE(v1.y, Ep);
            a6 += sigE(v1.z, Ep);
            a7 += sigE(v1.w, Ep);
        }
        s_part[tid] = ((a0 + a1) + (a2 + a3)) + ((a4 + a5) + (a6 + a7));
    }
    __syncthreads();
    if (tid < HALF) {
        float d = 0.5f + s_part[tid] + s_part[tid + HALF] + s_part[tid + 2 * HALF];
        s_inv[tid] = __builtin_amdgcn_rcpf(d);
    }
    __syncthreads();

    // --- phase B: entry-parallel over OWN half's entries, sigE 4-unroll ---
    const int* ent = h ? ent_hi : ent_lo;
    int n = nE3[1 + h];
    float part = 0.f;
    for (int e = tid; e < n; e += 576) {
        int pk = ent[e];
        int c = pk >> 16, p = pk & 0xFFFF;
        int off = s_off[c], m = s_off[c + 1] - off;
        float Ep = s_E[p];
        float b0 = 0.f, b1 = 0.f, b2 = 0.f, b3 = 0.f;
        int j = 0;
        for (; j + 3 < m; j += 4) {
            b0 += sigE(s_Eq[off + j], Ep);
            b1 += sigE(s_Eq[off + j + 1], Ep);
            b2 += sigE(s_Eq[off + j + 2], Ep);
            b3 += sigE(s_Eq[off + j + 3], Ep);
        }
        for (; j < m; ++j) b0 += sigE(s_Eq[off + j], Ep);
        float s = (b0 + b1) + (b2 + b3);
        // s includes q==p (=0.5): numerator = 0.5 + s
        part += (0.5f + s) * s_inv[p - h * HALF] * s_wsl[c];
    }

    for (int off = 32; off > 0; off >>= 1) part += __shfl_down(part, off, 64);
    if (lane == 0) s_red[wave] = part;
    __syncthreads();
    if (tid == 0) {
        float tot = 0.f;
#pragma unroll
        for (int w = 0; w < 9; ++w) tot += s_red[w];
        atomicAdd(out, -tot * (1.0f / (float)BB));
    }
}

extern "C" void kernel_launch(void* const* d_in, const int* in_sizes, int n_in,
                              void* d_out, int out_size, void* d_ws, size_t ws_size,
                              hipStream_t stream) {
    const float* preds = (const float*)d_in[0];       // (384,512) f32
    const float* softlabels = (const float*)d_in[1];  // (384,48) f32
    float* out = (float*)d_out;

    char* ws = (char*)d_ws;
    float*          simpart = (float*)(ws + 0);        // 4 * 589824 = 2359296
    float*          wclass  = (float*)(ws + 2359296);  // 192
    int*            cls_off = (int*)(ws + 2359488);    // 256 (49 used)
    unsigned short* plist   = (unsigned short*)(ws + 2359744);  // 6144
    int*            ent_lo  = (int*)(ws + 2365888);    // 12288
    int*            ent_hi  = (int*)(ws + 2378176);    // 12288
    int*            nE3     = (int*)(ws + 2390464);    // 12

    simprep_kernel<<<145, 256, 0, stream>>>(preds, softlabels, simpart, wclass,
                                            cls_off, plist, ent_lo, ent_hi, nE3, out);
    mega_kernel<<<BB * 2, 576, 0, stream>>>(simpart, softlabels, wclass, cls_off,
                                            plist, ent_lo, ent_hi, nE3, out);
}